// Round 2
// baseline (7048.179 us; speedup 1.0000x reference)
//
#include <hip/hip_runtime.h>
#include <cstdint>
#include <cstddef>

typedef unsigned short u16;
typedef unsigned int u32;

typedef __bf16 bf8_t __attribute__((ext_vector_type(8)));
typedef float f4_t __attribute__((ext_vector_type(4)));

__device__ __forceinline__ u16 f2bf(float x) {
  u32 u = __float_as_uint(x);
  u = (u + 0x7fffu + ((u >> 16) & 1u)) >> 16;
  return (u16)u;
}
__device__ __forceinline__ float bf2f(u16 x) {
  u32 u = ((u32)x) << 16;
  return __uint_as_float(u);
}
__device__ __forceinline__ float sigf(float x) { return 1.f / (1.f + __expf(-x)); }

// ---------------- fill (sentinel) ----------------
__global__ void fill_kernel(float* p, float v, long n) {
  long i = (long)blockIdx.x * blockDim.x + threadIdx.x;
  if (i < n) p[i] = v;
}

// ---------------- fp32 -> bf16 weight convert with zero padding ----------------
__global__ void padcvt_kernel(const float* __restrict__ src, u16* __restrict__ dst,
                              int rows, int cols, int pc, long total) {
  long i = (long)blockIdx.x * blockDim.x + threadIdx.x;
  if (i >= total) return;
  int r = (int)(i / pc), c = (int)(i % pc);
  float v = (r < rows && c < cols) ? src[(long)r * cols + c] : 0.f;
  dst[i] = f2bf(v);
}

// ---------------- token-shift mix (one target) ----------------
// h_b: batch base of hidden (global [T,H]); out_seg: compact [Tc,H] bf16.
__global__ void mix1_kernel(const float* __restrict__ h_b, const float* __restrict__ coef,
                            u16* __restrict__ out_seg, int t0, int Tc, long total4) {
  long i = (long)blockIdx.x * blockDim.x + threadIdx.x;
  if (i >= total4) return;
  long e = i * 4;
  const int H = 2048;
  int col = (int)(e % H);
  int tl = (int)(e / H);
  int tg = t0 + tl;
  const float* hp = h_b + (long)tg * H + col;
  float4 hv = *(const float4*)hp;
  float4 pv = make_float4(0.f, 0.f, 0.f, 0.f);
  if (tg > 0) pv = *(const float4*)(hp - H);
  float4 cc = *(const float4*)(coef + col);
  uint2 pk;
  pk.x = (u32)f2bf(hv.x + (pv.x - hv.x) * cc.x) | ((u32)f2bf(hv.y + (pv.y - hv.y) * cc.y) << 16);
  pk.y = (u32)f2bf(hv.z + (pv.z - hv.z) * cc.z) | ((u32)f2bf(hv.w + (pv.w - hv.w) * cc.w) << 16);
  *(uint2*)(out_seg + e) = pk;
}

// ---------------- bf16 MFMA GEMM: C[M,N] = A[M,K] * B[N,K]^T ----------------
// MODE 0: fp32 store. 1: bf16 store. 2: tanh->bf16. 3: sigmoid->bf16.
// MODE 4: lerp: C[id] = C[id] + (aux0[id]-C[id])*sigmoid(acc + aux1[n]) (fp32)
#define LDSW 40
template <int MODE>
__global__ __launch_bounds__(256) void gemm_bt(
    const u16* __restrict__ A, const u16* __restrict__ B, void* __restrict__ Cv,
    int M, int N, int K, const float* __restrict__ aux0, const float* __restrict__ aux1) {
  __shared__ u16 sA[128 * LDSW];
  __shared__ u16 sB[128 * LDSW];
  const int tid = threadIdx.x;
  const long bm = (long)blockIdx.y * 128;
  const long bn = (long)blockIdx.x * 128;
  const int wave = tid >> 6, lane = tid & 63;
  const int wm = (wave >> 1) * 64, wn = (wave & 1) * 64;
  const int quad = lane >> 4, rr = lane & 15;

  f4_t acc[4][4];
  const f4_t zero = {0.f, 0.f, 0.f, 0.f};
#pragma unroll
  for (int i = 0; i < 4; i++)
#pragma unroll
    for (int j = 0; j < 4; j++) acc[i][j] = zero;

  const int c0 = tid, c1 = tid + 256;
  for (int k0 = 0; k0 < K; k0 += 32) {
    __syncthreads();
    {
      const uint4 a0 = *(const uint4*)(A + (bm + (c0 >> 2)) * (long)K + k0 + (c0 & 3) * 8);
      const uint4 a1 = *(const uint4*)(A + (bm + (c1 >> 2)) * (long)K + k0 + (c1 & 3) * 8);
      const uint4 b0 = *(const uint4*)(B + (bn + (c0 >> 2)) * (long)K + k0 + (c0 & 3) * 8);
      const uint4 b1 = *(const uint4*)(B + (bn + (c1 >> 2)) * (long)K + k0 + (c1 & 3) * 8);
      *(uint4*)(&sA[(c0 >> 2) * LDSW + (c0 & 3) * 8]) = a0;
      *(uint4*)(&sA[(c1 >> 2) * LDSW + (c1 & 3) * 8]) = a1;
      *(uint4*)(&sB[(c0 >> 2) * LDSW + (c0 & 3) * 8]) = b0;
      *(uint4*)(&sB[(c1 >> 2) * LDSW + (c1 & 3) * 8]) = b1;
    }
    __syncthreads();
    bf8_t af[4], bfv[4];
#pragma unroll
    for (int i = 0; i < 4; i++)
      af[i] = *(const bf8_t*)(&sA[(wm + i * 16 + rr) * LDSW + quad * 8]);
#pragma unroll
    for (int j = 0; j < 4; j++)
      bfv[j] = *(const bf8_t*)(&sB[(wn + j * 16 + rr) * LDSW + quad * 8]);
#pragma unroll
    for (int i = 0; i < 4; i++)
#pragma unroll
      for (int j = 0; j < 4; j++)
        acc[i][j] = __builtin_amdgcn_mfma_f32_16x16x32_bf16(af[i], bfv[j], acc[i][j], 0, 0, 0);
  }
  // C/D: col = lane&15, row = quad*4 + reg
#pragma unroll
  for (int i = 0; i < 4; i++)
#pragma unroll
    for (int j = 0; j < 4; j++)
#pragma unroll
      for (int rg = 0; rg < 4; rg++) {
        long m = bm + wm + i * 16 + quad * 4 + rg;
        long n = bn + wn + j * 16 + rr;
        long id = m * (long)N + n;
        float x = acc[i][j][rg];
        if (MODE == 0) ((float*)Cv)[id] = x;
        else if (MODE == 1) ((u16*)Cv)[id] = f2bf(x);
        else if (MODE == 2) ((u16*)Cv)[id] = f2bf(tanhf(x));
        else if (MODE == 3) ((u16*)Cv)[id] = f2bf(sigf(x));
        else {  // lerp
          float* C = (float*)Cv;
          float vv = C[id];
          float sg = sigf(x + aux1[(int)n]);
          C[id] = vv + (aux0[id] - vv) * sg;
        }
      }
}

// ---------------- post-GEMM elementwise (wave per token-head) ----------------
// Fk: k-raw -> k_mod ; Fa: a-logit -> kk ; Fw: w-logit -> exp(decay) ; AV: bf16 sigmoid(a)
__global__ __launch_bounds__(256) void post1_kernel(
    float* Fk, float* Fa, float* Fw, u16* __restrict__ AV,
    const float* __restrict__ k_k, const float* __restrict__ k_a,
    const float* __restrict__ wb, const float* __restrict__ ab) {
  const int lane = threadIdx.x & 63;
  const long th = (((long)blockIdx.x * 256) + threadIdx.x) >> 6;
  const int hcol = (int)(th & 31) * 64 + lane;
  const long idx = th * 64 + lane;
  float kraw = Fk[idx];
  float kk0 = kraw * k_k[hcol];
  float ss = kk0 * kk0;
#pragma unroll
  for (int m = 32; m; m >>= 1) ss += __shfl_xor(ss, m, 64);
  float kkn = kk0 / fmaxf(sqrtf(ss), 1e-12f);
  float av = sigf(Fa[idx] + ab[hcol]);
  float dec = expf(-0.6065306597126334f * sigf(Fw[idx] + wb[hcol]));
  Fw[idx] = dec;
  Fk[idx] = kraw * (1.f + (av - 1.f) * k_a[hcol]);
  Fa[idx] = kkn;
  AV[idx] = f2bf(av);
}

// ---------------- RWKV7 scan: 4 waves per (b,head), k sliced by wave ----------------
// lane = v-row in every wave; wave w owns k in [16w,16w+16). o may alias dec.
__global__ __launch_bounds__(256) void scan4_kernel(
    const float* __restrict__ r, const float* __restrict__ dec, const float* __restrict__ km,
    const float* __restrict__ v, const float* __restrict__ kk, const u16* __restrict__ av,
    float* __restrict__ o, float* __restrict__ state, int Tc, int firstChunk) {
  const int tid = threadIdx.x;
  const int wv = tid >> 6, lane = tid & 63;
  const int bh = blockIdx.x;  // b*32 + h
  __shared__ float4 sh_p[64];
  __shared__ float sh_a[64];
  __shared__ float sh_sa[4][64];
  __shared__ float sh_o[4][64];
  float S[16];
  if (firstChunk) {
#pragma unroll
    for (int j = 0; j < 16; j++) S[j] = 0.f;
  } else {
#pragma unroll
    for (int j = 0; j < 16; j++) S[j] = state[((long)bh * 64 + lane) * 64 + wv * 16 + j];
  }
  const long base = ((long)(bh >> 5) * Tc * 32 + (bh & 31)) * 64;
  // prefetch registers
  float ld_d = 0.f, ld_kk = 0.f, ld_av = 0.f, ld_km = 0.f, ld_r = 0.f, ld_v;
  {
    long off = base + lane;
    if (wv == 0) {
      ld_d = dec[off]; ld_kk = kk[off]; ld_av = bf2f(av[off]); ld_km = km[off]; ld_r = r[off];
    }
    ld_v = v[off];
  }
  for (int t = 0; t < Tc; t++) {
    if (wv == 0) {
      sh_p[lane] = make_float4(ld_d, ld_kk * ld_av, ld_km, ld_r);
      sh_a[lane] = -ld_kk;
    }
    float vl = ld_v;
    if (t + 1 < Tc) {  // prefetch next step while this one computes
      long off = base + (long)(t + 1) * 2048 + lane;
      if (wv == 0) {
        ld_d = dec[off]; ld_kk = kk[off]; ld_av = bf2f(av[off]); ld_km = km[off]; ld_r = r[off];
      }
      ld_v = v[off];
    }
    __syncthreads();
    float sap = 0.f;
#pragma unroll
    for (int j = 0; j < 16; j++) sap += S[j] * sh_a[wv * 16 + j];
    sh_sa[wv][lane] = sap;
    __syncthreads();
    float sa = sh_sa[0][lane] + sh_sa[1][lane] + sh_sa[2][lane] + sh_sa[3][lane];
    float op = 0.f;
#pragma unroll
    for (int j = 0; j < 16; j++) {
      float4 p = sh_p[wv * 16 + j];
      float s = S[j] * p.x + sa * p.y + vl * p.z;
      S[j] = s;
      op += s * p.w;
    }
    sh_o[wv][lane] = op;
    __syncthreads();
    if (wv == 0)
      o[base + (long)t * 2048 + lane] =
          sh_o[0][lane] + sh_o[1][lane] + sh_o[2][lane] + sh_o[3][lane];
  }
#pragma unroll
  for (int j = 0; j < 16; j++) state[((long)bh * 64 + lane) * 64 + wv * 16 + j] = S[j];
}

// ---------------- group-norm + residual + gate ----------------
__global__ __launch_bounds__(256) void epi_kernel(
    const float* __restrict__ o, const float* __restrict__ r, const float* __restrict__ k,
    const float* __restrict__ v, const u16* __restrict__ g,
    const float* __restrict__ r_k, const float* __restrict__ gn_w, const float* __restrict__ gn_b,
    u16* __restrict__ y) {
  const int lane = threadIdx.x & 63;
  const long th = (((long)blockIdx.x * 256) + threadIdx.x) >> 6;
  const int hcol = (int)(th & 31) * 64 + lane;
  const long idx = th * 64 + lane;
  float ov = o[idx];
  float s = ov;
#pragma unroll
  for (int m = 32; m; m >>= 1) s += __shfl_xor(s, m, 64);
  float mu = s * (1.f / 64.f);
  float d = ov - mu;
  float vs = d * d;
#pragma unroll
  for (int m = 32; m; m >>= 1) vs += __shfl_xor(vs, m, 64);
  float on = d * rsqrtf(vs * (1.f / 64.f) + 6.4e-4f);
  on = on * gn_w[hcol] + gn_b[hcol];
  float rk = r[idx] * k[idx] * r_k[hcol];
#pragma unroll
  for (int m = 32; m; m >>= 1) rk += __shfl_xor(rk, m, 64);
  on += rk * v[idx];
  y[idx] = f2bf(on * bf2f(g[idx]));
}

// =============================== host ===============================
extern "C" void kernel_launch(void* const* d_in, const int* in_sizes, int n_in,
                              void* d_out, int out_size, void* d_ws, size_t ws_size,
                              hipStream_t stream) {
  constexpr int B = 2, T = 4096, H = 2048;
  const float* hst    = (const float*)d_in[0];
  const float* vfirst = (const float*)d_in[1];
  const float* x_r = (const float*)d_in[2];
  const float* x_w = (const float*)d_in[3];
  const float* x_k = (const float*)d_in[4];
  const float* x_v = (const float*)d_in[5];
  const float* x_a = (const float*)d_in[6];
  const float* x_g = (const float*)d_in[7];
  const float* k_k = (const float*)d_in[8];
  const float* k_a = (const float*)d_in[9];
  const float* r_k = (const float*)d_in[10];
  const float* w_r = (const float*)d_in[11];
  const float* w_k = (const float*)d_in[12];
  const float* w_v = (const float*)d_in[13];
  const float* w_o = (const float*)d_in[14];
  const float* wA  = (const float*)d_in[15];
  const float* wB  = (const float*)d_in[16];
  const float* wb  = (const float*)d_in[17];
  const float* aA  = (const float*)d_in[18];
  const float* aB  = (const float*)d_in[19];
  const float* ab  = (const float*)d_in[20];
  const float* vA  = (const float*)d_in[21];
  const float* vB  = (const float*)d_in[22];
  const float* vb  = (const float*)d_in[23];
  const float* gA  = (const float*)d_in[24];
  const float* gB  = (const float*)d_in[25];
  const float* gn_w= (const float*)d_in[26];
  const float* gn_b= (const float*)d_in[27];

  const size_t WEIGHT_BYTES = 4 * (size_t)H * H * 2      // w_r,w_k,w_v,w_o
                            + 6 * (size_t)128 * H * 2    // wA/aA/vA + wB/aB/vB (padded)
                            + 2 * (size_t)256 * H * 2;   // gA,gB
  const size_t STATE_BYTES = 64 * 64 * 64 * 4;

  // pick NC: smallest chunking that fits
  int NC = -1;
  for (int cand : {1, 2, 4, 8, 16, 32}) {
    long R = (long)B * T / cand;
    size_t need = (size_t)R * H * (5 * 4 + 3 * 2) + WEIGHT_BYTES + STATE_BYTES + (1 << 16);
    if (need <= ws_size) { NC = cand; break; }
  }
  const int BS = 256;
  auto cdiv = [](long a, long b) { return (int)((a + b - 1) / b); };
  if (NC < 0) {  // encode ws_size (MB) into sentinel
    fill_kernel<<<cdiv(out_size, BS), BS, 0, stream>>>(
        (float*)d_out, 200000.f + (float)(ws_size >> 20), out_size);
    return;
  }
  const int Tc = T / NC;
  const long R = (long)B * Tc;  // rows per chunk (both batches)
  const long RH = R * H;

  char* ws = (char*)d_ws;
  size_t off = 0;
  auto alloc = [&](size_t bytes) -> void* {
    void* p = ws + off;
    off += (bytes + 255) & ~(size_t)255;
    return p;
  };
  float* F0 = (float*)alloc(RH * 4);  // w-logit -> decay -> o
  float* F1 = (float*)alloc(RH * 4);  // k-raw -> k_mod
  float* F2 = (float*)alloc(RH * 4);  // v
  float* F3 = (float*)alloc(RH * 4);  // r (stage-1 lora aliased here first)
  float* F4 = (float*)alloc(RH * 4);  // a-logit -> kk
  u16* MIXB = (u16*)alloc(RH * 2);    // mix input, later y
  u16* AV   = (u16*)alloc(RH * 2);
  u16* G    = (u16*)alloc(RH * 2);
  u16* wrb = (u16*)alloc((size_t)H * H * 2);
  u16* wkb = (u16*)alloc((size_t)H * H * 2);
  u16* wvb = (u16*)alloc((size_t)H * H * 2);
  u16* wob = (u16*)alloc((size_t)H * H * 2);
  u16* wAb = (u16*)alloc((size_t)128 * H * 2);
  u16* wBb = (u16*)alloc((size_t)H * 128 * 2);
  u16* aAb = (u16*)alloc((size_t)128 * H * 2);
  u16* aBb = (u16*)alloc((size_t)H * 128 * 2);
  u16* vAb = (u16*)alloc((size_t)128 * H * 2);
  u16* vBb = (u16*)alloc((size_t)H * 128 * 2);
  u16* gAb = (u16*)alloc((size_t)256 * H * 2);
  u16* gBb = (u16*)alloc((size_t)H * 256 * 2);
  float* state = (float*)alloc(STATE_BYTES);
  u16* s1b = (u16*)F3;  // stage-1 lora bf16 [R,128/256], F3 dead until r-GEMM

  // weights -> bf16 (once)
  padcvt_kernel<<<cdiv((long)H * H, BS), BS, 0, stream>>>(w_r, wrb, H, H, H, (long)H * H);
  padcvt_kernel<<<cdiv((long)H * H, BS), BS, 0, stream>>>(w_k, wkb, H, H, H, (long)H * H);
  padcvt_kernel<<<cdiv((long)H * H, BS), BS, 0, stream>>>(w_v, wvb, H, H, H, (long)H * H);
  padcvt_kernel<<<cdiv((long)H * H, BS), BS, 0, stream>>>(w_o, wob, H, H, H, (long)H * H);
  padcvt_kernel<<<cdiv((long)128 * H, BS), BS, 0, stream>>>(wA, wAb, 96, H, H, (long)128 * H);
  padcvt_kernel<<<cdiv((long)H * 128, BS), BS, 0, stream>>>(wB, wBb, H, 96, 128, (long)H * 128);
  padcvt_kernel<<<cdiv((long)128 * H, BS), BS, 0, stream>>>(aA, aAb, 96, H, H, (long)128 * H);
  padcvt_kernel<<<cdiv((long)H * 128, BS), BS, 0, stream>>>(aB, aBb, H, 96, 128, (long)H * 128);
  padcvt_kernel<<<cdiv((long)128 * H, BS), BS, 0, stream>>>(vA, vAb, 64, H, H, (long)128 * H);
  padcvt_kernel<<<cdiv((long)H * 128, BS), BS, 0, stream>>>(vB, vBb, H, 64, 128, (long)H * 128);
  padcvt_kernel<<<cdiv((long)256 * H, BS), BS, 0, stream>>>(gA, gAb, 256, H, H, (long)256 * H);
  padcvt_kernel<<<cdiv((long)H * 256, BS), BS, 0, stream>>>(gB, gBb, H, 256, 256, (long)H * 256);

  const long mixTot = (long)Tc * H / 4;
  const int mixG = cdiv(mixTot, BS);
  const int ehG = (int)(R * 32 / 4);  // post1/epi grids (256 thr = 4 token-heads)

  for (int c = 0; c < NC; c++) {
    const int t0 = c * Tc;
    auto MIX = [&](const float* coef) {
      for (int b = 0; b < B; b++)
        mix1_kernel<<<mixG, BS, 0, stream>>>(hst + (long)b * T * H, coef,
                                             MIXB + (long)b * Tc * H, t0, Tc, mixTot);
    };
    dim3 gN128(1, (unsigned)(R / 128)), gN256(2, (unsigned)(R / 128)), gBig(16, (unsigned)(R / 128));
    // w-lora
    MIX(x_w);
    gemm_bt<2><<<gN128, 256, 0, stream>>>(MIXB, wAb, s1b, (int)R, 128, H, nullptr, nullptr);
    gemm_bt<0><<<gBig, 256, 0, stream>>>(s1b, wBb, F0, (int)R, H, 128, nullptr, nullptr);
    // a-lora
    MIX(x_a);
    gemm_bt<1><<<gN128, 256, 0, stream>>>(MIXB, aAb, s1b, (int)R, 128, H, nullptr, nullptr);
    gemm_bt<0><<<gBig, 256, 0, stream>>>(s1b, aBb, F4, (int)R, H, 128, nullptr, nullptr);
    // v: raw projection + lerp lora
    MIX(x_v);
    gemm_bt<0><<<gBig, 256, 0, stream>>>(MIXB, wvb, F2, (int)R, H, H, nullptr, nullptr);
    gemm_bt<1><<<gN128, 256, 0, stream>>>(MIXB, vAb, s1b, (int)R, 128, H, nullptr, nullptr);
    for (int b = 0; b < B; b++) {
      dim3 gHalf(16, (unsigned)(Tc / 128));
      gemm_bt<4><<<gHalf, 256, 0, stream>>>(s1b + (long)b * Tc * 128, vBb,
                                            F2 + (long)b * Tc * H, Tc, H, 128,
                                            vfirst + ((long)b * T + t0) * H, vb);
    }
    // g-lora
    MIX(x_g);
    gemm_bt<3><<<gN256, 256, 0, stream>>>(MIXB, gAb, s1b, (int)R, 256, H, nullptr, nullptr);
    gemm_bt<1><<<gBig, 256, 0, stream>>>(s1b, gBb, G, (int)R, H, 256, nullptr, nullptr);
    // r, k projections
    MIX(x_r);
    gemm_bt<0><<<gBig, 256, 0, stream>>>(MIXB, wrb, F3, (int)R, H, H, nullptr, nullptr);
    MIX(x_k);
    gemm_bt<0><<<gBig, 256, 0, stream>>>(MIXB, wkb, F1, (int)R, H, H, nullptr, nullptr);
    // elementwise: decay, k_mod, kk, av
    post1_kernel<<<ehG, 256, 0, stream>>>(F1, F4, F0, AV, k_k, k_a, wb, ab);
    // scan (o in-place into F0)
    scan4_kernel<<<64, 256, 0, stream>>>(F3, F0, F1, F2, F4, AV, F0, state, Tc, c == 0);
    // groupnorm + residual + gate -> MIXB (bf16)
    epi_kernel<<<ehG, 256, 0, stream>>>(F0, F3, F1, F2, G, r_k, gn_w, gn_b, MIXB);
    // output projection
    for (int b = 0; b < B; b++) {
      dim3 gHalf(16, (unsigned)(Tc / 128));
      gemm_bt<0><<<gHalf, 256, 0, stream>>>(MIXB + (long)b * Tc * H, wob,
                                            (float*)d_out + ((long)b * T + t0) * H,
                                            Tc, H, H, nullptr, nullptr);
    }
  }
}

// Round 3
// 3687.485 us; speedup vs baseline: 1.9114x; 1.9114x over previous
//
#include <hip/hip_runtime.h>
#include <cstdint>
#include <cstddef>

typedef unsigned short u16;
typedef unsigned int u32;

typedef __bf16 bf8_t __attribute__((ext_vector_type(8)));
typedef float f4_t __attribute__((ext_vector_type(4)));

__device__ __forceinline__ u16 f2bf(float x) {
  u32 u = __float_as_uint(x);
  u = (u + 0x7fffu + ((u >> 16) & 1u)) >> 16;
  return (u16)u;
}
__device__ __forceinline__ float bf2f(u16 x) {
  u32 u = ((u32)x) << 16;
  return __uint_as_float(u);
}
__device__ __forceinline__ float sigf(float x) { return 1.f / (1.f + __expf(-x)); }

#define MFMA16(a, b, c) __builtin_amdgcn_mfma_f32_16x16x32_bf16(a, b, c, 0, 0, 0)

// ---------------- fill (sentinel) ----------------
__global__ void fill_kernel(float* p, float v, long n) {
  long i = (long)blockIdx.x * blockDim.x + threadIdx.x;
  if (i < n) p[i] = v;
}

// ---------------- fp32 -> bf16 weight convert with zero padding ----------------
__global__ void padcvt_kernel(const float* __restrict__ src, u16* __restrict__ dst,
                              int rows, int cols, int pc, long total) {
  long i = (long)blockIdx.x * blockDim.x + threadIdx.x;
  if (i >= total) return;
  int r = (int)(i / pc), c = (int)(i % pc);
  float v = (r < rows && c < cols) ? src[(long)r * cols + c] : 0.f;
  dst[i] = f2bf(v);
}

// ---------------- token-shift mix ----------------
__global__ void mix1_kernel(const float* __restrict__ h_b, const float* __restrict__ coef,
                            u16* __restrict__ out_seg, int t0, int Tc, long total4) {
  long i = (long)blockIdx.x * blockDim.x + threadIdx.x;
  if (i >= total4) return;
  long e = i * 4;
  const int H = 2048;
  int col = (int)(e % H);
  int tl = (int)(e / H);
  int tg = t0 + tl;
  const float* hp = h_b + (long)tg * H + col;
  float4 hv = *(const float4*)hp;
  float4 pv = make_float4(0.f, 0.f, 0.f, 0.f);
  if (tg > 0) pv = *(const float4*)(hp - H);
  float4 cc = *(const float4*)(coef + col);
  uint2 pk;
  pk.x = (u32)f2bf(hv.x + (pv.x - hv.x) * cc.x) | ((u32)f2bf(hv.y + (pv.y - hv.y) * cc.y) << 16);
  pk.y = (u32)f2bf(hv.z + (pv.z - hv.z) * cc.z) | ((u32)f2bf(hv.w + (pv.w - hv.w) * cc.w) << 16);
  *(uint2*)(out_seg + e) = pk;
}

// ---------------- bf16 MFMA GEMM: C[M,N] = A[M,K] * B[N,K]^T ----------------
// MODE 0: fp32. 1: bf16. 2: tanh->bf16. 3: sigmoid->bf16. 4: fp32 lerp epilogue.
#define LDSW 40
template <int MODE>
__global__ __launch_bounds__(256) void gemm_bt(
    const u16* __restrict__ A, const u16* __restrict__ B, void* __restrict__ Cv,
    int M, int N, int K, const float* __restrict__ aux0, const float* __restrict__ aux1) {
  __shared__ u16 sA[128 * LDSW];
  __shared__ u16 sB[128 * LDSW];
  const int tid = threadIdx.x;
  const long bm = (long)blockIdx.y * 128;
  const long bn = (long)blockIdx.x * 128;
  const int wave = tid >> 6, lane = tid & 63;
  const int wm = (wave >> 1) * 64, wn = (wave & 1) * 64;
  const int quad = lane >> 4, rr = lane & 15;

  f4_t acc[4][4];
  const f4_t zero = {0.f, 0.f, 0.f, 0.f};
#pragma unroll
  for (int i = 0; i < 4; i++)
#pragma unroll
    for (int j = 0; j < 4; j++) acc[i][j] = zero;

  const int c0 = tid, c1 = tid + 256;
  for (int k0 = 0; k0 < K; k0 += 32) {
    __syncthreads();
    {
      const uint4 a0 = *(const uint4*)(A + (bm + (c0 >> 2)) * (long)K + k0 + (c0 & 3) * 8);
      const uint4 a1 = *(const uint4*)(A + (bm + (c1 >> 2)) * (long)K + k0 + (c1 & 3) * 8);
      const uint4 b0 = *(const uint4*)(B + (bn + (c0 >> 2)) * (long)K + k0 + (c0 & 3) * 8);
      const uint4 b1 = *(const uint4*)(B + (bn + (c1 >> 2)) * (long)K + k0 + (c1 & 3) * 8);
      *(uint4*)(&sA[(c0 >> 2) * LDSW + (c0 & 3) * 8]) = a0;
      *(uint4*)(&sA[(c1 >> 2) * LDSW + (c1 & 3) * 8]) = a1;
      *(uint4*)(&sB[(c0 >> 2) * LDSW + (c0 & 3) * 8]) = b0;
      *(uint4*)(&sB[(c1 >> 2) * LDSW + (c1 & 3) * 8]) = b1;
    }
    __syncthreads();
    bf8_t af[4], bfv[4];
#pragma unroll
    for (int i = 0; i < 4; i++)
      af[i] = *(const bf8_t*)(&sA[(wm + i * 16 + rr) * LDSW + quad * 8]);
#pragma unroll
    for (int j = 0; j < 4; j++)
      bfv[j] = *(const bf8_t*)(&sB[(wn + j * 16 + rr) * LDSW + quad * 8]);
#pragma unroll
    for (int i = 0; i < 4; i++)
#pragma unroll
      for (int j = 0; j < 4; j++)
        acc[i][j] = MFMA16(af[i], bfv[j], acc[i][j]);
  }
#pragma unroll
  for (int i = 0; i < 4; i++)
#pragma unroll
    for (int j = 0; j < 4; j++)
#pragma unroll
      for (int rg = 0; rg < 4; rg++) {
        long m = bm + wm + i * 16 + quad * 4 + rg;
        long n = bn + wn + j * 16 + rr;
        long id = m * (long)N + n;
        float x = acc[i][j][rg];
        if (MODE == 0) ((float*)Cv)[id] = x;
        else if (MODE == 1) ((u16*)Cv)[id] = f2bf(x);
        else if (MODE == 2) ((u16*)Cv)[id] = f2bf(tanhf(x));
        else if (MODE == 3) ((u16*)Cv)[id] = f2bf(sigf(x));
        else {
          float* C = (float*)Cv;
          float vv = C[id];
          float sg = sigf(x + aux1[(int)n]);
          C[id] = vv + (aux0[id] - vv) * sg;
        }
      }
}

// ---------------- post-GEMM elementwise ----------------
// F1: k-raw (fp32) ; F4: a-logit ; F0: w-logit -> w (log-decay fp32, in place) ; F2: v (fp32)
// outs bf16: KM (k_mod), KK (kk), BB (kk*av), VB (v)
__global__ __launch_bounds__(256) void post1_kernel(
    const float* __restrict__ F1, const float* __restrict__ F4, float* F0,
    const float* __restrict__ F2,
    u16* __restrict__ KM, u16* __restrict__ KK, u16* __restrict__ BB, u16* __restrict__ VB,
    const float* __restrict__ k_k, const float* __restrict__ k_a,
    const float* __restrict__ wb, const float* __restrict__ ab) {
  const int lane = threadIdx.x & 63;
  const long th = (((long)blockIdx.x * 256) + threadIdx.x) >> 6;
  const int hcol = (int)(th & 31) * 64 + lane;
  const long idx = th * 64 + lane;
  float kraw = F1[idx];
  float kk0 = kraw * k_k[hcol];
  float ss = kk0 * kk0;
#pragma unroll
  for (int m = 32; m; m >>= 1) ss += __shfl_xor(ss, m, 64);
  float kkn = kk0 / fmaxf(sqrtf(ss), 1e-12f);
  float av = sigf(F4[idx] + ab[hcol]);
  float w = -0.6065306597126334f * sigf(F0[idx] + wb[hcol]);
  F0[idx] = w;
  KM[idx] = f2bf(kraw * (1.f + (av - 1.f) * k_a[hcol]));
  KK[idx] = f2bf(kkn);
  BB[idx] = f2bf(kkn * av);
  VB[idx] = f2bf(F2[idx]);
}

// ================= chunked RWKV7 scan (L=16) =================
// Recurrence: S_t = S_{t-1} diag(d_t) + (S_{t-1} a_t) b_t^T + v_t k_t^T, a=-kk, b=kk*av.
// Per chunk: A_ij=<b_j*e^{cw_{i-1}-cw_j},a_i> (j<i), B_ij same with k, P/Q incl diag with r.
// U=(I-A)^{-1}(B V + Xa S0^T); O = [P TW + Q V] + (Xr + P TA) S0^T;
// S_L = S0*diag(cl) + S0*G + Z,  Z=(TW^T Ya + V^T Yb)*dcl, G^T = YaT*dcl . TAt.
constexpr int ST64 = 72;   // u16 stride for [16][64]
constexpr int ST32 = 40;   // u16 stride for [.][32]
constexpr int STX = 132;   // fp32 stride for X [16][128]

__global__ __launch_bounds__(64) void phaseA_kernel(
    const float* __restrict__ wS, const u16* __restrict__ kmS, const u16* __restrict__ kkS,
    const u16* __restrict__ bbS, const u16* __restrict__ vbS, const u16* __restrict__ rbS,
    float* __restrict__ POWb, u16* __restrict__ PAb, float* __restrict__ Zb,
    u16* __restrict__ GTb, float* __restrict__ CLb, int Tc, int sp0) {
  __shared__ u16 lXa[16 * ST64], lXr[16 * ST64], lYa[16 * ST64], lYb[16 * ST64];
  __shared__ u16 lYaT[64 * ST32], lYbT[64 * ST32], lVmT[64 * ST32];
  __shared__ u16 lTWt[64 * ST32], lTAt[64 * ST32];
  __shared__ u16 lP[16 * ST32], lQ[16 * ST32], lBm[16 * ST32];
  __shared__ float lA[16 * 16];
  __shared__ float lX[16 * STX];
  __shared__ float lcl[64];
  const int lane = threadIdx.x;
  const int quad = lane >> 4, l15 = lane & 15;
  const long tile = blockIdx.x;
  const int bh = (int)(tile & 63);
  const int col = (int)(tile >> 6);
  const int b = bh >> 5, h = bh & 31;
  const long s = tile;
  const f4_t z4 = {0.f, 0.f, 0.f, 0.f};

  // zero kdim pad (cols 16..31) of 32-wide operand matrices
  {
    u32* p0 = (u32*)&lYaT[lane * ST32 + 16];
    u32* p1 = (u32*)&lYbT[lane * ST32 + 16];
    u32* p2 = (u32*)&lVmT[lane * ST32 + 16];
    u32* p3 = (u32*)&lTWt[lane * ST32 + 16];
    u32* p4 = (u32*)&lTAt[lane * ST32 + 16];
#pragma unroll
    for (int q = 0; q < 8; q++) { p0[q] = 0; p1[q] = 0; p2[q] = 0; p3[q] = 0; p4[q] = 0; }
    if (lane < 16) {
      u32* q0 = (u32*)&lP[lane * ST32 + 16];
      u32* q1 = (u32*)&lQ[lane * ST32 + 16];
      u32* q2 = (u32*)&lBm[lane * ST32 + 16];
#pragma unroll
      for (int q = 0; q < 8; q++) { q0[q] = 0; q1[q] = 0; q2[q] = 0; }
    }
  }

  // ---- staging: cumulative decay + scaled matrices ----
  const long rowbase = (long)b * Tc + (long)(sp0 + col) * 16;
  const long gbase = rowbase * 2048 + (long)h * 64 + lane;
  float cw = 0.f;
#pragma unroll
  for (int i = 0; i < 16; i++) {
    long g = gbase + (long)i * 2048;
    float w = wS[g];
    float km = bf2f(kmS[g]), kk = bf2f(kkS[g]), bb = bf2f(bbS[g]);
    float vv = bf2f(vbS[g]), rr2 = bf2f(rbS[g]);
    float cwm = cw;
    cw += w;
    float E1 = __expf(cwm), E2 = __expf(-cw), E3 = __expf(cw);
    float xa = -kk * E1;
    lXa[i * ST64 + lane] = f2bf(xa);
    lX[i * STX + 64 + lane] = xa;
    lXr[i * ST64 + lane] = f2bf(rr2 * E3);
    float ya = bb * E2, yb = km * E2;
    lYa[i * ST64 + lane] = f2bf(ya);
    lYb[i * ST64 + lane] = f2bf(yb);
    lYaT[lane * ST32 + i] = f2bf(ya);
    lYbT[lane * ST32 + i] = f2bf(yb);
    lVmT[lane * ST32 + i] = f2bf(vv);
    if (i == 15) { lcl[lane] = E3; CLb[s * 64 + lane] = E3; }
  }
  __syncthreads();

  // ---- A, Bm, P, Q (16x16, kdim 64) ----
  {
    f4_t aA = z4, aB = z4, aP = z4, aQ = z4;
#pragma unroll
    for (int kc = 0; kc < 2; kc++) {
      bf8_t xa = *(const bf8_t*)&lXa[l15 * ST64 + quad * 8 + 32 * kc];
      bf8_t xr = *(const bf8_t*)&lXr[l15 * ST64 + quad * 8 + 32 * kc];
      bf8_t ya = *(const bf8_t*)&lYa[l15 * ST64 + quad * 8 + 32 * kc];
      bf8_t yb = *(const bf8_t*)&lYb[l15 * ST64 + quad * 8 + 32 * kc];
      aA = MFMA16(xa, ya, aA);
      aB = MFMA16(xa, yb, aB);
      aP = MFMA16(xr, ya, aP);
      aQ = MFMA16(xr, yb, aQ);
    }
#pragma unroll
    for (int rg = 0; rg < 4; rg++) {
      int m = quad * 4 + rg;
      lA[m * 16 + l15] = (l15 < m) ? aA[rg] : 0.f;
      lBm[m * ST32 + l15] = (l15 < m) ? f2bf(aB[rg]) : (u16)0;
      lP[m * ST32 + l15] = (l15 <= m) ? f2bf(aP[rg]) : (u16)0;
      lQ[m * ST32 + l15] = (l15 <= m) ? f2bf(aQ[rg]) : (u16)0;
    }
  }
  __syncthreads();

  // ---- X[:,0:64] = Bm * Vm ----
#pragma unroll
  for (int nt = 0; nt < 4; nt++) {
    f4_t acc = z4;
    bf8_t a = *(const bf8_t*)&lBm[l15 * ST32 + quad * 8];
    bf8_t bb2 = *(const bf8_t*)&lVmT[(nt * 16 + l15) * ST32 + quad * 8];
    acc = MFMA16(a, bb2, acc);
#pragma unroll
    for (int rg = 0; rg < 4; rg++) lX[(quad * 4 + rg) * STX + nt * 16 + l15] = acc[rg];
  }
  __syncthreads();

  // ---- forward substitution: X = (I - A)^{-1} X  (lane owns cols lane, lane+64) ----
  for (int i = 1; i < 16; i++) {
    float x0 = lX[i * STX + lane], x1 = lX[i * STX + 64 + lane];
    for (int j = 0; j < i; j++) {
      float aij = lA[i * 16 + j];
      x0 += aij * lX[j * STX + lane];
      x1 += aij * lX[j * STX + 64 + lane];
    }
    lX[i * STX + lane] = x0;
    lX[i * STX + 64 + lane] = x1;
  }
  // transposed bf16 copies: TWt[v][i] = X[i][v], TAt[k][i] = X[i][64+k]
#pragma unroll
  for (int i = 0; i < 16; i++) {
    lTWt[lane * ST32 + i] = f2bf(lX[i * STX + lane]);
    lTAt[lane * ST32 + i] = f2bf(lX[i * STX + 64 + lane]);
  }
  __syncthreads();

  // ---- POW = P*TW + Q*Vm ; PA = Xr + P*TA ----
#pragma unroll
  for (int nt = 0; nt < 4; nt++) {
    f4_t acc = z4;
    bf8_t p = *(const bf8_t*)&lP[l15 * ST32 + quad * 8];
    bf8_t q = *(const bf8_t*)&lQ[l15 * ST32 + quad * 8];
    bf8_t tw = *(const bf8_t*)&lTWt[(nt * 16 + l15) * ST32 + quad * 8];
    bf8_t vm = *(const bf8_t*)&lVmT[(nt * 16 + l15) * ST32 + quad * 8];
    acc = MFMA16(p, tw, acc);
    acc = MFMA16(q, vm, acc);
#pragma unroll
    for (int rg = 0; rg < 4; rg++)
      POWb[s * 1024 + (quad * 4 + rg) * 64 + nt * 16 + l15] = acc[rg];
  }
#pragma unroll
  for (int nt = 0; nt < 4; nt++) {
    f4_t acc = z4;
    bf8_t p = *(const bf8_t*)&lP[l15 * ST32 + quad * 8];
    bf8_t ta = *(const bf8_t*)&lTAt[(nt * 16 + l15) * ST32 + quad * 8];
    acc = MFMA16(p, ta, acc);
#pragma unroll
    for (int rg = 0; rg < 4; rg++) {
      float xr = bf2f(lXr[(quad * 4 + rg) * ST64 + nt * 16 + l15]);
      PAb[s * 1024 + (quad * 4 + rg) * 64 + nt * 16 + l15] = f2bf(acc[rg] + xr);
    }
  }

  // ---- Z[v][k] = (TWt.Ya + VmT.Yb)*cl[k] ;  GT[k][j] = cl[k]*(YaT.TAt) ----
#pragma unroll
  for (int mt = 0; mt < 4; mt++)
#pragma unroll
    for (int nt = 0; nt < 4; nt++) {
      f4_t acc = z4;
      bf8_t tw = *(const bf8_t*)&lTWt[(mt * 16 + l15) * ST32 + quad * 8];
      bf8_t vm = *(const bf8_t*)&lVmT[(mt * 16 + l15) * ST32 + quad * 8];
      bf8_t yat = *(const bf8_t*)&lYaT[(nt * 16 + l15) * ST32 + quad * 8];
      bf8_t ybt = *(const bf8_t*)&lYbT[(nt * 16 + l15) * ST32 + quad * 8];
      acc = MFMA16(tw, yat, acc);
      acc = MFMA16(vm, ybt, acc);
      float cl = lcl[nt * 16 + l15];
#pragma unroll
      for (int rg = 0; rg < 4; rg++)
        Zb[s * 4096 + (mt * 16 + quad * 4 + rg) * 64 + nt * 16 + l15] = acc[rg] * cl;
    }
#pragma unroll
  for (int mt = 0; mt < 4; mt++)
#pragma unroll
    for (int nt = 0; nt < 4; nt++) {
      f4_t acc = z4;
      bf8_t yat = *(const bf8_t*)&lYaT[(mt * 16 + l15) * ST32 + quad * 8];
      bf8_t ta = *(const bf8_t*)&lTAt[(nt * 16 + l15) * ST32 + quad * 8];
      acc = MFMA16(yat, ta, acc);
#pragma unroll
      for (int rg = 0; rg < 4; rg++) {
        float cl = lcl[mt * 16 + quad * 4 + rg];
        GTb[s * 4096 + (mt * 16 + quad * 4 + rg) * 64 + nt * 16 + l15] = f2bf(acc[rg] * cl);
      }
    }
}

// phase B: sequential state propagation per (b,h). S_new = S*cl + Sbf*G + Z.
__global__ __launch_bounds__(256) void phaseB_kernel(
    const float* __restrict__ Zb, const u16* __restrict__ GTb, const float* __restrict__ CLb,
    u16* __restrict__ S0b, float* __restrict__ state, int CT, int init) {
  __shared__ u16 Sb[64 * ST64];
  const int bh = blockIdx.x;
  const int tid = threadIdx.x, wv = tid >> 6, lane = tid & 63;
  const int quad = lane >> 4, l15 = lane & 15;
  float S[4][4];
  if (init) {
#pragma unroll
    for (int nt = 0; nt < 4; nt++)
#pragma unroll
      for (int rg = 0; rg < 4; rg++) S[nt][rg] = 0.f;
  } else {
#pragma unroll
    for (int nt = 0; nt < 4; nt++)
#pragma unroll
      for (int rg = 0; rg < 4; rg++)
        S[nt][rg] = state[(long)bh * 4096 + (16 * wv + quad * 4 + rg) * 64 + nt * 16 + l15];
  }
  const f4_t z4 = {0.f, 0.f, 0.f, 0.f};
  for (int c = 0; c < CT; c++) {
    long s = (long)c * 64 + bh;
#pragma unroll
    for (int nt = 0; nt < 4; nt++)
#pragma unroll
      for (int rg = 0; rg < 4; rg++)
        Sb[(16 * wv + quad * 4 + rg) * ST64 + nt * 16 + l15] = f2bf(S[nt][rg]);
    __syncthreads();
    f4_t acc[4] = {z4, z4, z4, z4};
#pragma unroll
    for (int kc = 0; kc < 2; kc++) {
      bf8_t a = *(const bf8_t*)&Sb[(16 * wv + l15) * ST64 + quad * 8 + 32 * kc];
      // checkpoint S0 (pre-update) to global, coalesced 16B
      *(uint4*)(S0b + s * 4096 + (16 * wv + l15) * 64 + quad * 8 + 32 * kc) = *(uint4*)&a;
#pragma unroll
      for (int nt = 0; nt < 4; nt++) {
        bf8_t g = *(const bf8_t*)(GTb + s * 4096 + (nt * 16 + l15) * 64 + quad * 8 + 32 * kc);
        acc[nt] = MFMA16(a, g, acc[nt]);
      }
    }
#pragma unroll
    for (int nt = 0; nt < 4; nt++) {
      float cl = CLb[s * 64 + nt * 16 + l15];
#pragma unroll
      for (int rg = 0; rg < 4; rg++) {
        float z = Zb[s * 4096 + (16 * wv + quad * 4 + rg) * 64 + nt * 16 + l15];
        S[nt][rg] = S[nt][rg] * cl + acc[nt][rg] + z;
      }
    }
    __syncthreads();
  }
#pragma unroll
  for (int nt = 0; nt < 4; nt++)
#pragma unroll
    for (int rg = 0; rg < 4; rg++)
      state[(long)bh * 4096 + (16 * wv + quad * 4 + rg) * 64 + nt * 16 + l15] = S[nt][rg];
}

// phase C: O = POW + PA * S0^T  (one wave per tile, frags straight from global)
__global__ __launch_bounds__(64) void phaseC_kernel(
    const float* __restrict__ POWb, const u16* __restrict__ PAb, const u16* __restrict__ S0b,
    float* __restrict__ O, int Tc, int sp0) {
  const int lane = threadIdx.x, quad = lane >> 4, l15 = lane & 15;
  const long tile = blockIdx.x;
  const int bh = (int)(tile & 63), col = (int)(tile >> 6);
  const int b = bh >> 5, h = bh & 31;
  const long s = tile;
  const f4_t z4 = {0.f, 0.f, 0.f, 0.f};
  f4_t acc[4] = {z4, z4, z4, z4};
#pragma unroll
  for (int kc = 0; kc < 2; kc++) {
    bf8_t a = *(const bf8_t*)(PAb + s * 1024 + l15 * 64 + quad * 8 + 32 * kc);
#pragma unroll
    for (int nt = 0; nt < 4; nt++) {
      bf8_t bo = *(const bf8_t*)(S0b + s * 4096 + (nt * 16 + l15) * 64 + quad * 8 + 32 * kc);
      acc[nt] = MFMA16(a, bo, acc[nt]);
    }
  }
  const long rowbase = (long)b * Tc + (long)(sp0 + col) * 16;
#pragma unroll
  for (int nt = 0; nt < 4; nt++)
#pragma unroll
    for (int rg = 0; rg < 4; rg++) {
      int i = quad * 4 + rg, v = nt * 16 + l15;
      float p = POWb[s * 1024 + i * 64 + v];
      O[(rowbase + i) * 2048 + (long)h * 64 + v] = p + acc[nt][rg];
    }
}

// ---------------- group-norm + residual + gate ----------------
__global__ __launch_bounds__(256) void epi_kernel(
    const float* __restrict__ o, const u16* __restrict__ r, const u16* __restrict__ k,
    const u16* __restrict__ v, const u16* __restrict__ g,
    const float* __restrict__ r_k, const float* __restrict__ gn_w, const float* __restrict__ gn_b,
    u16* __restrict__ y) {
  const int lane = threadIdx.x & 63;
  const long th = (((long)blockIdx.x * 256) + threadIdx.x) >> 6;
  const int hcol = (int)(th & 31) * 64 + lane;
  const long idx = th * 64 + lane;
  float ov = o[idx];
  float s = ov;
#pragma unroll
  for (int m = 32; m; m >>= 1) s += __shfl_xor(s, m, 64);
  float mu = s * (1.f / 64.f);
  float d = ov - mu;
  float vs = d * d;
#pragma unroll
  for (int m = 32; m; m >>= 1) vs += __shfl_xor(vs, m, 64);
  float on = d * rsqrtf(vs * (1.f / 64.f) + 6.4e-4f);
  on = on * gn_w[hcol] + gn_b[hcol];
  float rk = bf2f(r[idx]) * bf2f(k[idx]) * r_k[hcol];
#pragma unroll
  for (int m = 32; m; m >>= 1) rk += __shfl_xor(rk, m, 64);
  on += rk * bf2f(v[idx]);
  y[idx] = f2bf(on * bf2f(g[idx]));
}

// =============================== host ===============================
extern "C" void kernel_launch(void* const* d_in, const int* in_sizes, int n_in,
                              void* d_out, int out_size, void* d_ws, size_t ws_size,
                              hipStream_t stream) {
  constexpr int B = 2, T = 4096, H = 2048;
  const float* hst    = (const float*)d_in[0];
  const float* vfirst = (const float*)d_in[1];
  const float* x_r = (const float*)d_in[2];
  const float* x_w = (const float*)d_in[3];
  const float* x_k = (const float*)d_in[4];
  const float* x_v = (const float*)d_in[5];
  const float* x_a = (const float*)d_in[6];
  const float* x_g = (const float*)d_in[7];
  const float* k_k = (const float*)d_in[8];
  const float* k_a = (const float*)d_in[9];
  const float* r_k = (const float*)d_in[10];
  const float* w_r = (const float*)d_in[11];
  const float* w_k = (const float*)d_in[12];
  const float* w_v = (const float*)d_in[13];
  const float* w_o = (const float*)d_in[14];
  const float* wA  = (const float*)d_in[15];
  const float* wB  = (const float*)d_in[16];
  const float* wb  = (const float*)d_in[17];
  const float* aA  = (const float*)d_in[18];
  const float* aB  = (const float*)d_in[19];
  const float* ab  = (const float*)d_in[20];
  const float* vA  = (const float*)d_in[21];
  const float* vB  = (const float*)d_in[22];
  const float* vb  = (const float*)d_in[23];
  const float* gA  = (const float*)d_in[24];
  const float* gB  = (const float*)d_in[25];
  const float* gn_w= (const float*)d_in[26];
  const float* gn_b= (const float*)d_in[27];

  const size_t WEIGHT_BYTES = 4 * (size_t)H * H * 2 + 6 * (size_t)128 * H * 2
                            + 2 * (size_t)256 * H * 2;
  const size_t STATE_BYTES = (size_t)64 * 4096 * 4;
  const size_t TILE_BYTES = 4096 + 2048 + 16384 + 8192 + 256 + 8192;  // POW PA Z GT CL S0

  int NC = -1, CT = 0;
  for (int pass = 0; pass < 2 && NC < 0; pass++) {
    for (int nc : {1, 2, 4, 8, 16}) {
      long Tc_ = T / nc;
      long R_ = (long)B * Tc_;
      long RH_ = R_ * H;
      size_t base = (size_t)RH_ * 16 + (size_t)RH_ * 10 + (size_t)RH_ * 4 + (size_t)R_ * 512
                  + WEIGHT_BYTES + STATE_BYTES + (1 << 20);
      int cols = (int)(Tc_ / 16);
      int found = 0;
      for (int ct : {64, 32, 16, 8}) {
        if (ct > cols) continue;
        if (pass == 0 && ct < 16) continue;
        size_t need = base + (size_t)64 * ct * TILE_BYTES;
        if (need <= ws_size) { NC = nc; CT = ct; found = 1; break; }
      }
      if (found) break;
    }
  }
  const int BS = 256;
  auto cdiv = [](long a, long b) { return (int)((a + b - 1) / b); };
  if (NC < 0) {
    fill_kernel<<<cdiv(out_size, BS), BS, 0, stream>>>(
        (float*)d_out, 200000.f + (float)(ws_size >> 20), out_size);
    return;
  }
  const int Tc = T / NC;
  const long R = (long)B * Tc;
  const long RH = R * H;
  const int cols = Tc / 16;
  const int NTILE = 64 * CT;

  char* ws = (char*)d_ws;
  size_t off = 0;
  auto alloc = [&](size_t bytes) -> void* {
    void* p = ws + off;
    off += (bytes + 255) & ~(size_t)255;
    return p;
  };
  float* F0 = (float*)alloc(RH * 4);   // w-logit -> w (log-decay)
  float* F1 = (float*)alloc(RH * 4);   // k-raw ; later O (scan output)
  float* F2 = (float*)alloc(RH * 4);   // v (post-lerp)
  float* F4 = (float*)alloc(RH * 4);   // a-logit
  u16* KM  = (u16*)alloc(RH * 2);
  u16* KK  = (u16*)alloc(RH * 2);
  u16* BBs = (u16*)alloc(RH * 2);
  u16* VBs = (u16*)alloc(RH * 2);
  u16* RBs = (u16*)alloc(RH * 2);
  u16* MIXB = (u16*)alloc(RH * 2);
  u16* G    = (u16*)alloc(RH * 2);
  u16* s1b  = (u16*)alloc(R * 512);
  u16* wrb = (u16*)alloc((size_t)H * H * 2);
  u16* wkb = (u16*)alloc((size_t)H * H * 2);
  u16* wvb = (u16*)alloc((size_t)H * H * 2);
  u16* wob = (u16*)alloc((size_t)H * H * 2);
  u16* wAb = (u16*)alloc((size_t)128 * H * 2);
  u16* wBb = (u16*)alloc((size_t)H * 128 * 2);
  u16* aAb = (u16*)alloc((size_t)128 * H * 2);
  u16* aBb = (u16*)alloc((size_t)H * 128 * 2);
  u16* vAb = (u16*)alloc((size_t)128 * H * 2);
  u16* vBb = (u16*)alloc((size_t)H * 128 * 2);
  u16* gAb = (u16*)alloc((size_t)256 * H * 2);
  u16* gBb = (u16*)alloc((size_t)H * 256 * 2);
  float* state = (float*)alloc(STATE_BYTES);
  float* POWb = (float*)alloc((size_t)NTILE * 4096);
  u16*   PAb  = (u16*)alloc((size_t)NTILE * 2048);
  float* Zb   = (float*)alloc((size_t)NTILE * 16384);
  u16*   GTb  = (u16*)alloc((size_t)NTILE * 8192);
  float* CLb  = (float*)alloc((size_t)NTILE * 256);
  u16*   S0b  = (u16*)alloc((size_t)NTILE * 8192);
  float* Ob = F1;  // scan output aliases F1 (k-raw dead after post1)

  // weights -> bf16 (once)
  padcvt_kernel<<<cdiv((long)H * H, BS), BS, 0, stream>>>(w_r, wrb, H, H, H, (long)H * H);
  padcvt_kernel<<<cdiv((long)H * H, BS), BS, 0, stream>>>(w_k, wkb, H, H, H, (long)H * H);
  padcvt_kernel<<<cdiv((long)H * H, BS), BS, 0, stream>>>(w_v, wvb, H, H, H, (long)H * H);
  padcvt_kernel<<<cdiv((long)H * H, BS), BS, 0, stream>>>(w_o, wob, H, H, H, (long)H * H);
  padcvt_kernel<<<cdiv((long)128 * H, BS), BS, 0, stream>>>(wA, wAb, 96, H, H, (long)128 * H);
  padcvt_kernel<<<cdiv((long)H * 128, BS), BS, 0, stream>>>(wB, wBb, H, 96, 128, (long)H * 128);
  padcvt_kernel<<<cdiv((long)128 * H, BS), BS, 0, stream>>>(aA, aAb, 96, H, H, (long)128 * H);
  padcvt_kernel<<<cdiv((long)H * 128, BS), BS, 0, stream>>>(aB, aBb, H, 96, 128, (long)H * 128);
  padcvt_kernel<<<cdiv((long)128 * H, BS), BS, 0, stream>>>(vA, vAb, 64, H, H, (long)128 * H);
  padcvt_kernel<<<cdiv((long)H * 128, BS), BS, 0, stream>>>(vB, vBb, H, 64, 128, (long)H * 128);
  padcvt_kernel<<<cdiv((long)256 * H, BS), BS, 0, stream>>>(gA, gAb, 256, H, H, (long)256 * H);
  padcvt_kernel<<<cdiv((long)H * 256, BS), BS, 0, stream>>>(gB, gBb, H, 256, 256, (long)H * 256);

  const long mixTot = (long)Tc * H / 4;
  const int mixG = cdiv(mixTot, BS);
  const int ehG = (int)(R * 32 / 4);

  for (int c = 0; c < NC; c++) {
    const int t0 = c * Tc;
    auto MIX = [&](const float* coef) {
      for (int b = 0; b < B; b++)
        mix1_kernel<<<mixG, BS, 0, stream>>>(hst + (long)b * T * H, coef,
                                             MIXB + (long)b * Tc * H, t0, Tc, mixTot);
    };
    dim3 gN128(1, (unsigned)(R / 128)), gN256(2, (unsigned)(R / 128)), gBig(16, (unsigned)(R / 128));
    // w-lora -> F0 (w-logit)
    MIX(x_w);
    gemm_bt<2><<<gN128, 256, 0, stream>>>(MIXB, wAb, s1b, (int)R, 128, H, nullptr, nullptr);
    gemm_bt<0><<<gBig, 256, 0, stream>>>(s1b, wBb, F0, (int)R, H, 128, nullptr, nullptr);
    // a-lora -> F4
    MIX(x_a);
    gemm_bt<1><<<gN128, 256, 0, stream>>>(MIXB, aAb, s1b, (int)R, 128, H, nullptr, nullptr);
    gemm_bt<0><<<gBig, 256, 0, stream>>>(s1b, aBb, F4, (int)R, H, 128, nullptr, nullptr);
    // v: raw proj + lerp
    MIX(x_v);
    gemm_bt<0><<<gBig, 256, 0, stream>>>(MIXB, wvb, F2, (int)R, H, H, nullptr, nullptr);
    gemm_bt<1><<<gN128, 256, 0, stream>>>(MIXB, vAb, s1b, (int)R, 128, H, nullptr, nullptr);
    for (int b = 0; b < B; b++) {
      dim3 gHalf(16, (unsigned)(Tc / 128));
      gemm_bt<4><<<gHalf, 256, 0, stream>>>(s1b + (long)b * Tc * 128, vBb,
                                            F2 + (long)b * Tc * H, Tc, H, 128,
                                            vfirst + ((long)b * T + t0) * H, vb);
    }
    // g-lora -> G
    MIX(x_g);
    gemm_bt<3><<<gN256, 256, 0, stream>>>(MIXB, gAb, s1b, (int)R, 256, H, nullptr, nullptr);
    gemm_bt<1><<<gBig, 256, 0, stream>>>(s1b, gBb, G, (int)R, H, 256, nullptr, nullptr);
    // r -> RBs (bf16), k -> F1 (fp32)
    MIX(x_r);
    gemm_bt<1><<<gBig, 256, 0, stream>>>(MIXB, wrb, RBs, (int)R, H, H, nullptr, nullptr);
    MIX(x_k);
    gemm_bt<0><<<gBig, 256, 0, stream>>>(MIXB, wkb, F1, (int)R, H, H, nullptr, nullptr);
    // elementwise
    post1_kernel<<<ehG, 256, 0, stream>>>(F1, F4, F0, F2, KM, KK, BBs, VBs,
                                          k_k, k_a, wb, ab);
    // chunked scan
    for (int sp = 0; sp < cols; sp += CT) {
      phaseA_kernel<<<NTILE, 64, 0, stream>>>(F0, KM, KK, BBs, VBs, RBs,
                                              POWb, PAb, Zb, GTb, CLb, Tc, sp);
      phaseB_kernel<<<64, 256, 0, stream>>>(Zb, GTb, CLb, S0b, state, CT,
                                            (c == 0 && sp == 0) ? 1 : 0);
      phaseC_kernel<<<NTILE, 64, 0, stream>>>(POWb, PAb, S0b, Ob, Tc, sp);
    }
    // groupnorm + residual + gate -> MIXB
    epi_kernel<<<ehG, 256, 0, stream>>>(Ob, RBs, KM, VBs, G, r_k, gn_w, gn_b, MIXB);
    // output projection
    for (int b = 0; b < B; b++) {
      dim3 gHalf(16, (unsigned)(Tc / 128));
      gemm_bt<0><<<gHalf, 256, 0, stream>>>(MIXB + (long)b * Tc * H, wob,
                                            (float*)d_out + ((long)b * T + t0) * H,
                                            Tc, H, H, nullptr, nullptr);
    }
  }
}